// Round 3
// baseline (1713.561 us; speedup 1.0000x reference)
//
#include <hip/hip_runtime.h>
#include <math.h>

typedef unsigned long long u64;
typedef __attribute__((ext_vector_type(2))) unsigned long long u64x2;

#define NB 8192
#define NS 4096

// ws layout (bytes):
//   [0,16K)       pcnt[2048] u64      (K1 per-block nonzero count)
//   [16K,32K)     p3[2048]   double   (K3 per-block partial sums)
//   [32K,32K+4M)  maskbitsT[64][8192] u64   (bit-packed mask, word-transposed)
//   [+4M,+6M)     wbitsT[64][4096]    u64   (bit-packed W columns, word-transposed)
static const size_t OFF_CNT = 0;
static const size_t OFF_P3  = 16384;
static const size_t OFF_MB  = 32768;
static const size_t OFF_WB  = OFF_MB + (size_t)64 * 8192 * 8;

// Bit convention: word gw covers elements [gw*64, gw*64+64); bit p of the word
// corresponds to element offset 4*(p&15) + (p>>4). (Order-invariant under the
// AND+popcount contraction as long as K1 and K2 agree.)

// ---------------- K1: pack mask bits (transposed) + count nonzeros ----------------
__global__ __launch_bounds__(256) void k1_pack_mask(
    const float* __restrict__ y, u64* __restrict__ mbT, u64* __restrict__ pcnt)
{
    __shared__ unsigned rc[4];
    const unsigned t = threadIdx.x;
    const unsigned lane = t & 63;
    const float4* y4 = (const float4*)y;
    u64 qi = (u64)blockIdx.x * 256 + t;       // float4 index
    const u64 stride = (u64)2048 * 256;       // 2^19
    unsigned lcnt = 0;
    #pragma unroll 4
    for (int it = 0; it < 16; ++it, qi += stride) {
        float4 v = y4[qi];
        u64 b0 = __ballot(v.x != 0.0f);
        u64 b1 = __ballot(v.y != 0.0f);
        u64 b2 = __ballot(v.z != 0.0f);
        u64 b3 = __ballot(v.w != 0.0f);
        lcnt += (v.x != 0.0f) + (v.y != 0.0f) + (v.z != 0.0f) + (v.w != 0.0f);
        if (lane < 4) {
            unsigned sh = lane << 4;
            u64 word = ((b0 >> sh) & 0xFFFFull)
                     | (((b1 >> sh) & 0xFFFFull) << 16)
                     | (((b2 >> sh) & 0xFFFFull) << 32)
                     | (((b3 >> sh) & 0xFFFFull) << 48);
            u64 gw = ((qi - lane) >> 4) + lane;        // word index, lane=g
            mbT[((gw & 63) << 13) + (gw >> 6)] = word;
        }
    }
    for (int off = 32; off; off >>= 1) lcnt += __shfl_down(lcnt, off, 64);
    if ((t & 63) == 0) rc[t >> 6] = lcnt;
    __syncthreads();
    if (t == 0) pcnt[blockIdx.x] = (u64)rc[0] + rc[1] + rc[2] + rc[3];
}

// ---------------- K2: pack W rows into bit columns (transposed, permuted bit order) ----------------
__global__ __launch_bounds__(256) void k2_pack_w(
    const float* __restrict__ W, u64* __restrict__ wbT)
{
    __shared__ float tile[64][65];
    const int j0 = blockIdx.x * 64;
    const int w  = blockIdx.y;            // W-row block: rows w*64..w*64+63
    const int i0 = w * 64;
    const int t = threadIdx.x;
    #pragma unroll
    for (int k = 0; k < 16; ++k) {
        int lin = t + (k << 8);
        int r = lin >> 6, c = lin & 63;
        tile[r][c] = W[(size_t)(i0 + r) * NS + (j0 + c)];
    }
    __syncthreads();
    const int lane = t & 63;
    const int wv = t >> 6;
    const int pr = ((lane & 15) << 2) + (lane >> 4);   // bit l <-> row offset 4*(l&15)+(l>>4)
    for (int jj = wv; jj < 64; jj += 4) {
        u64 bal = __ballot(tile[pr][jj] != 0.0f);
        if (lane == 0) wbT[((size_t)w << 12) + (j0 + jj)] = bal;
    }
}

// ---------------- K3: 128x128 tile popcount-GEMM, 4x16-w stages, fused epilogue ----------------
__global__ __launch_bounds__(256, 4) void k3_main(
    const float* __restrict__ y, const float* __restrict__ yhat,
    const u64* __restrict__ mbT, const u64* __restrict__ wbT,
    double* __restrict__ p3)
{
    __shared__ alignas(16) u64 mT[16 * 128];   // [w][r] linear, 16KB
    __shared__ alignas(16) u64 wT[16 * 128];   // [w][c] XOR-swizzled chunks, 16KB
    const int b0 = blockIdx.x << 7;            // 64 row-tiles
    const int j0 = blockIdx.y << 7;            // 32 col-tiles
    const int t  = threadIdx.x;
    const int r0 = (t >> 4) << 3;              // 8 rows per thread
    const int cj = t & 15;                     // col-group; c0 = cj*8
    const unsigned sx = ((unsigned)cj >> 2) << 4;   // swizzle byte-XOR for q reads

    unsigned cnt[8][8];
    #pragma unroll
    for (int a = 0; a < 8; ++a)
        #pragma unroll
        for (int b = 0; b < 8; ++b) cnt[a][b] = 0;

    char* mB = (char*)mT;
    char* wB = (char*)wT;

    #pragma unroll 1
    for (int s = 0; s < 4; ++s) {
        // load this stage's 16 w-rows into regs (short-lived)
        u64x2 gm[4], gq[4];
        #pragma unroll
        for (int k = 0; k < 4; ++k) {
            int lin = t + (k << 8);
            int wl = (s << 4) + (lin >> 6), c2 = lin & 63;
            gm[k] = *(const u64x2*)&mbT[((size_t)wl << 13) + b0 + 2 * c2];
            gq[k] = *(const u64x2*)&wbT[((size_t)wl << 12) + j0 + 2 * c2];
        }
        __syncthreads();   // previous stage's compute done before overwrite
        #pragma unroll
        for (int k = 0; k < 4; ++k) {
            int lin = t + (k << 8);
            int wl = lin >> 6, c2 = lin & 63;
            int p = c2 ^ ((c2 >> 4) & 3);
            *(u64x2*)(mB + (wl << 10) + (c2 << 4)) = gm[k];
            *(u64x2*)(wB + (wl << 10) + (p << 4)) = gq[k];
        }
        __syncthreads();

        unsigned mo = (unsigned)(r0 << 3);
        unsigned qs = (unsigned)(cj << 6) + sx;
        #pragma unroll 2
        for (int w = 0; w < 16; ++w) {
            unsigned ml[16], ql[16];
            #pragma unroll
            for (int k = 0; k < 4; ++k) {
                uint4 a = *(const uint4*)(mB + mo + (k << 4));
                ml[4 * k + 0] = a.x; ml[4 * k + 1] = a.y;
                ml[4 * k + 2] = a.z; ml[4 * k + 3] = a.w;
                uint4 b = *(const uint4*)(wB + (qs ^ (unsigned)(k << 4)));
                ql[4 * k + 0] = b.x; ql[4 * k + 1] = b.y;
                ql[4 * k + 2] = b.z; ql[4 * k + 3] = b.w;
            }
            #pragma unroll
            for (int aa = 0; aa < 8; ++aa)
                #pragma unroll
                for (int bb = 0; bb < 8; ++bb) {
                    cnt[aa][bb] += __popc(ml[2 * aa] & ql[2 * bb]);
                    cnt[aa][bb] += __popc(ml[2 * aa + 1] & ql[2 * bb + 1]);
                }
            mo += 1024; qs += 1024;
        }
    }

    // epilogue: part = sum sq * (mask + 0.1*cnt) over this thread's 8x8 patch
    float part = 0.0f;
    const int c0 = cj << 3;
    #pragma unroll
    for (int aa = 0; aa < 8; ++aa) {
        size_t off = ((size_t)(b0 + r0 + aa) << 12) + (size_t)(j0 + c0);
        float ys[8], hs[8];
        *(float4*)&ys[0] = *(const float4*)(y + off);
        *(float4*)&ys[4] = *(const float4*)(y + off + 4);
        *(float4*)&hs[0] = *(const float4*)(yhat + off);
        *(float4*)&hs[4] = *(const float4*)(yhat + off + 4);
        #pragma unroll
        for (int bb = 0; bb < 8; ++bb) {
            float e = ys[bb] - hs[bb];
            float wgt = 0.1f * (float)cnt[aa][bb] + (ys[bb] != 0.0f ? 1.0f : 0.0f);
            part = fmaf(e * e, wgt, part);
        }
    }

    for (int off = 32; off; off >>= 1) part += __shfl_down(part, off, 64);
    float* red = (float*)mT;    // safe: barrier below before aliasing
    __syncthreads();
    if ((t & 63) == 0) red[t >> 6] = part;
    __syncthreads();
    if (t == 0)
        p3[(size_t)blockIdx.y * gridDim.x + blockIdx.x] =
            (double)red[0] + (double)red[1] + (double)red[2] + (double)red[3];
}

// ---------------- K4: final reduce + sqrt ----------------
__global__ __launch_bounds__(256) void k4_final(
    const u64* __restrict__ pcnt, const double* __restrict__ p3, float* __restrict__ out)
{
    __shared__ double rs[4];
    __shared__ u64 rcc[4];
    double s3 = 0.0;
    u64 c = 0;
    for (int i = threadIdx.x; i < 2048; i += 256) { s3 += p3[i]; c += pcnt[i]; }
    for (int off = 32; off; off >>= 1) {
        s3 += __shfl_down(s3, off, 64);
        c  += __shfl_down(c, off, 64);
    }
    int wv = threadIdx.x >> 6;
    if ((threadIdx.x & 63) == 0) { rs[wv] = s3; rcc[wv] = c; }
    __syncthreads();
    if (threadIdx.x == 0) {
        double S3 = rs[0] + rs[1] + rs[2] + rs[3];
        double C  = (double)(rcc[0] + rcc[1] + rcc[2] + rcc[3]);
        out[0] = (float)sqrt(S3 / C + 1e-6);
    }
}

extern "C" void kernel_launch(void* const* d_in, const int* in_sizes, int n_in,
                              void* d_out, int out_size, void* d_ws, size_t ws_size,
                              hipStream_t stream) {
    const float* yhat = (const float*)d_in[0];
    const float* y    = (const float*)d_in[1];
    const float* W    = (const float*)d_in[2];
    char* ws = (char*)d_ws;
    u64*    pcnt = (u64*)(ws + OFF_CNT);
    double* p3   = (double*)(ws + OFF_P3);
    u64*    mbT  = (u64*)(ws + OFF_MB);
    u64*    wbT  = (u64*)(ws + OFF_WB);

    k1_pack_mask<<<dim3(2048), dim3(256), 0, stream>>>(y, mbT, pcnt);
    k2_pack_w<<<dim3(64, 64), dim3(256), 0, stream>>>(W, wbT);
    k3_main<<<dim3(64, 32), dim3(256), 0, stream>>>(y, yhat, mbT, wbT, p3);
    k4_final<<<dim3(1), dim3(256), 0, stream>>>(pcnt, p3, (float*)d_out);
}

// Round 5
// 357.274 us; speedup vs baseline: 4.7962x; 4.7962x over previous
//
#include <hip/hip_runtime.h>
#include <math.h>

typedef unsigned long long u64;
typedef __attribute__((ext_vector_type(2))) unsigned long long u64x2;

#define NB 8192
#define NS 4096

// ws layout (bytes):
//   [0,16K)       pcnt[2048] u64      (K1 per-block nonzero count)
//   [16K,32K)     p3[2048]   double   (K3 per-block partial sums)
//   [32K,32K+4M)  maskbitsT[64][8192] u64   (bit-packed mask, word-transposed)
//   [+4M,+6M)     wbitsT[64][4096]    u64   (bit-packed W columns, word-transposed)
static const size_t OFF_CNT = 0;
static const size_t OFF_P3  = 16384;
static const size_t OFF_MB  = 32768;
static const size_t OFF_WB  = OFF_MB + (size_t)64 * 8192 * 8;

// Bit convention: word gw covers elements [gw*64, gw*64+64); bit p of the word
// corresponds to element offset 4*(p&15) + (p>>4). (Order-invariant under the
// AND+popcount contraction as long as K1 and K2 agree.)

// ---------------- K1: pack mask bits (transposed) + count nonzeros ----------------
__global__ __launch_bounds__(256) void k1_pack_mask(
    const float* __restrict__ y, u64* __restrict__ mbT, u64* __restrict__ pcnt)
{
    __shared__ unsigned rc[4];
    const unsigned t = threadIdx.x;
    const unsigned lane = t & 63;
    const float4* y4 = (const float4*)y;
    u64 qi = (u64)blockIdx.x * 256 + t;       // float4 index
    const u64 stride = (u64)2048 * 256;       // 2^19
    unsigned lcnt = 0;
    #pragma unroll 4
    for (int it = 0; it < 16; ++it, qi += stride) {
        float4 v = y4[qi];
        u64 b0 = __ballot(v.x != 0.0f);
        u64 b1 = __ballot(v.y != 0.0f);
        u64 b2 = __ballot(v.z != 0.0f);
        u64 b3 = __ballot(v.w != 0.0f);
        lcnt += (v.x != 0.0f) + (v.y != 0.0f) + (v.z != 0.0f) + (v.w != 0.0f);
        if (lane < 4) {
            unsigned sh = lane << 4;
            u64 word = ((b0 >> sh) & 0xFFFFull)
                     | (((b1 >> sh) & 0xFFFFull) << 16)
                     | (((b2 >> sh) & 0xFFFFull) << 32)
                     | (((b3 >> sh) & 0xFFFFull) << 48);
            u64 gw = ((qi - lane) >> 4) + lane;        // word index, lane=g
            mbT[((gw & 63) << 13) + (gw >> 6)] = word;
        }
    }
    for (int off = 32; off; off >>= 1) lcnt += __shfl_down(lcnt, off, 64);
    if ((t & 63) == 0) rc[t >> 6] = lcnt;
    __syncthreads();
    if (t == 0) pcnt[blockIdx.x] = (u64)rc[0] + rc[1] + rc[2] + rc[3];
}

// ---------------- K2: pack W rows into bit columns (transposed, permuted bit order) ----------------
__global__ __launch_bounds__(256) void k2_pack_w(
    const float* __restrict__ W, u64* __restrict__ wbT)
{
    __shared__ float tile[64][65];
    const int j0 = blockIdx.x * 64;
    const int w  = blockIdx.y;            // W-row block: rows w*64..w*64+63
    const int i0 = w * 64;
    const int t = threadIdx.x;
    #pragma unroll
    for (int k = 0; k < 16; ++k) {
        int lin = t + (k << 8);
        int r = lin >> 6, c = lin & 63;
        tile[r][c] = W[(size_t)(i0 + r) * NS + (j0 + c)];
    }
    __syncthreads();
    const int lane = t & 63;
    const int wv = t >> 6;
    const int pr = ((lane & 15) << 2) + (lane >> 4);   // bit l <-> row offset 4*(l&15)+(l>>4)
    for (int jj = wv; jj < 64; jj += 4) {
        u64 bal = __ballot(tile[pr][jj] != 0.0f);
        if (lane == 0) wbT[((size_t)w << 12) + (j0 + jj)] = bal;
    }
}

// ---------------- K3: 128x128 tile popcount-GEMM, 4x16-w stages, fused epilogue ----------------
__global__ __launch_bounds__(256, 2) void k3_main(
    const float* __restrict__ y, const float* __restrict__ yhat,
    const u64* __restrict__ mbT, const u64* __restrict__ wbT,
    double* __restrict__ p3)
{
    __shared__ alignas(16) u64 mT[16 * 128];   // [w][r] linear, 16KB
    __shared__ alignas(16) u64 wT[16 * 128];   // [w][c] XOR-swizzled chunks, 16KB
    const int b0 = blockIdx.x << 7;            // 64 row-tiles
    const int j0 = blockIdx.y << 7;            // 32 col-tiles
    const int t  = threadIdx.x;
    const int r0 = (t >> 4) << 3;              // 8 rows per thread
    const int cj = t & 15;                     // col-group; c0 = cj*8
    const unsigned sx = ((unsigned)cj >> 2) << 4;   // swizzle byte-XOR for q reads

    unsigned cnt[8][8];
    #pragma unroll
    for (int a = 0; a < 8; ++a)
        #pragma unroll
        for (int b = 0; b < 8; ++b) cnt[a][b] = 0;

    char* mB = (char*)mT;
    char* wB = (char*)wT;

    #pragma unroll 1
    for (int s = 0; s < 4; ++s) {
        // load this stage's 16 w-rows into regs (short-lived, consumed immediately)
        u64x2 gm[4], gq[4];
        #pragma unroll
        for (int k = 0; k < 4; ++k) {
            int lin = t + (k << 8);
            int wl = (s << 4) + (lin >> 6), c2 = lin & 63;
            gm[k] = *(const u64x2*)&mbT[((size_t)wl << 13) + b0 + 2 * c2];
            gq[k] = *(const u64x2*)&wbT[((size_t)wl << 12) + j0 + 2 * c2];
        }
        __syncthreads();   // previous stage's compute done before overwrite
        #pragma unroll
        for (int k = 0; k < 4; ++k) {
            int lin = t + (k << 8);
            int wl = lin >> 6, c2 = lin & 63;
            int p = c2 ^ ((c2 >> 4) & 3);
            *(u64x2*)(mB + (wl << 10) + (c2 << 4)) = gm[k];
            *(u64x2*)(wB + (wl << 10) + (p << 4)) = gq[k];
        }
        __syncthreads();

        unsigned mo = (unsigned)(r0 << 3);
        unsigned qs = (unsigned)(cj << 6) + sx;
        #pragma unroll 2
        for (int w = 0; w < 16; ++w) {
            unsigned ml[16], ql[16];
            #pragma unroll
            for (int k = 0; k < 4; ++k) {
                uint4 a = *(const uint4*)(mB + mo + (k << 4));
                ml[4 * k + 0] = a.x; ml[4 * k + 1] = a.y;
                ml[4 * k + 2] = a.z; ml[4 * k + 3] = a.w;
                uint4 b = *(const uint4*)(wB + (qs ^ (unsigned)(k << 4)));
                ql[4 * k + 0] = b.x; ql[4 * k + 1] = b.y;
                ql[4 * k + 2] = b.z; ql[4 * k + 3] = b.w;
            }
            #pragma unroll
            for (int aa = 0; aa < 8; ++aa)
                #pragma unroll
                for (int bb = 0; bb < 8; ++bb) {
                    cnt[aa][bb] += __popc(ml[2 * aa] & ql[2 * bb]);
                    cnt[aa][bb] += __popc(ml[2 * aa + 1] & ql[2 * bb + 1]);
                }
            mo += 1024; qs += 1024;
        }
    }

    // epilogue: part = sum sq * (mask + 0.1*cnt) over this thread's 8x8 patch
    float part = 0.0f;
    const int c0 = cj << 3;
    #pragma unroll
    for (int aa = 0; aa < 8; ++aa) {
        size_t off = ((size_t)(b0 + r0 + aa) << 12) + (size_t)(j0 + c0);
        float ys[8], hs[8];
        *(float4*)&ys[0] = *(const float4*)(y + off);
        *(float4*)&ys[4] = *(const float4*)(y + off + 4);
        *(float4*)&hs[0] = *(const float4*)(yhat + off);
        *(float4*)&hs[4] = *(const float4*)(yhat + off + 4);
        #pragma unroll
        for (int bb = 0; bb < 8; ++bb) {
            float e = ys[bb] - hs[bb];
            float wgt = 0.1f * (float)cnt[aa][bb] + (ys[bb] != 0.0f ? 1.0f : 0.0f);
            part = fmaf(e * e, wgt, part);
        }
    }

    for (int off = 32; off; off >>= 1) part += __shfl_down(part, off, 64);
    float* red = (float*)mT;    // safe: barrier below before aliasing
    __syncthreads();
    if ((t & 63) == 0) red[t >> 6] = part;
    __syncthreads();
    if (t == 0)
        p3[(size_t)blockIdx.y * gridDim.x + blockIdx.x] =
            (double)red[0] + (double)red[1] + (double)red[2] + (double)red[3];
}

// ---------------- K4: final reduce + sqrt ----------------
__global__ __launch_bounds__(256) void k4_final(
    const u64* __restrict__ pcnt, const double* __restrict__ p3, float* __restrict__ out)
{
    __shared__ double rs[4];
    __shared__ u64 rcc[4];
    double s3 = 0.0;
    u64 c = 0;
    for (int i = threadIdx.x; i < 2048; i += 256) { s3 += p3[i]; c += pcnt[i]; }
    for (int off = 32; off; off >>= 1) {
        s3 += __shfl_down(s3, off, 64);
        c  += __shfl_down(c, off, 64);
    }
    int wv = threadIdx.x >> 6;
    if ((threadIdx.x & 63) == 0) { rs[wv] = s3; rcc[wv] = c; }
    __syncthreads();
    if (threadIdx.x == 0) {
        double S3 = rs[0] + rs[1] + rs[2] + rs[3];
        double C  = (double)(rcc[0] + rcc[1] + rcc[2] + rcc[3]);
        out[0] = (float)sqrt(S3 / C + 1e-6);
    }
}

extern "C" void kernel_launch(void* const* d_in, const int* in_sizes, int n_in,
                              void* d_out, int out_size, void* d_ws, size_t ws_size,
                              hipStream_t stream) {
    const float* yhat = (const float*)d_in[0];
    const float* y    = (const float*)d_in[1];
    const float* W    = (const float*)d_in[2];
    char* ws = (char*)d_ws;
    u64*    pcnt = (u64*)(ws + OFF_CNT);
    double* p3   = (double*)(ws + OFF_P3);
    u64*    mbT  = (u64*)(ws + OFF_MB);
    u64*    wbT  = (u64*)(ws + OFF_WB);

    k1_pack_mask<<<dim3(2048), dim3(256), 0, stream>>>(y, mbT, pcnt);
    k2_pack_w<<<dim3(64, 64), dim3(256), 0, stream>>>(W, wbT);
    k3_main<<<dim3(64, 32), dim3(256), 0, stream>>>(y, yhat, mbT, wbT, p3);
    k4_final<<<dim3(1), dim3(256), 0, stream>>>(pcnt, p3, (float*)d_out);
}

// Round 6
// 354.714 us; speedup vs baseline: 4.8308x; 1.0072x over previous
//
#include <hip/hip_runtime.h>
#include <math.h>

typedef unsigned long long u64;
typedef __attribute__((ext_vector_type(2))) unsigned long long u64x2;

#define NB 8192
#define NS 4096

// ws layout (bytes):
//   [0,16K)       pcnt[2048] u64      (K1 per-block nonzero count)
//   [16K,32K)     p3[2048]   double   (K3 per-block partial sums)
//   [32K,32K+4M)  maskbitsT[64][8192] u64   (bit-packed mask, word-transposed)
//   [+4M,+6M)     wbitsT[64][4096]    u64   (bit-packed W columns, word-transposed)
static const size_t OFF_CNT = 0;
static const size_t OFF_P3  = 16384;
static const size_t OFF_MB  = 32768;
static const size_t OFF_WB  = OFF_MB + (size_t)64 * 8192 * 8;

// Bit convention: word gw covers elements [gw*64, gw*64+64); bit p of the word
// corresponds to element offset 4*(p&15) + (p>>4). (Order-invariant under the
// AND+popcount contraction as long as K1 and K2 agree.)

// ---------------- K1: pack mask bits (transposed) + count nonzeros ----------------
__global__ __launch_bounds__(256) void k1_pack_mask(
    const float* __restrict__ y, u64* __restrict__ mbT, u64* __restrict__ pcnt)
{
    __shared__ unsigned rc[4];
    const unsigned t = threadIdx.x;
    const unsigned lane = t & 63;
    const float4* y4 = (const float4*)y;
    u64 qi = (u64)blockIdx.x * 256 + t;       // float4 index
    const u64 stride = (u64)2048 * 256;       // 2^19
    unsigned lcnt = 0;
    #pragma unroll 4
    for (int it = 0; it < 16; ++it, qi += stride) {
        float4 v = y4[qi];
        u64 b0 = __ballot(v.x != 0.0f);
        u64 b1 = __ballot(v.y != 0.0f);
        u64 b2 = __ballot(v.z != 0.0f);
        u64 b3 = __ballot(v.w != 0.0f);
        lcnt += (v.x != 0.0f) + (v.y != 0.0f) + (v.z != 0.0f) + (v.w != 0.0f);
        if (lane < 4) {
            unsigned sh = lane << 4;
            u64 word = ((b0 >> sh) & 0xFFFFull)
                     | (((b1 >> sh) & 0xFFFFull) << 16)
                     | (((b2 >> sh) & 0xFFFFull) << 32)
                     | (((b3 >> sh) & 0xFFFFull) << 48);
            u64 gw = ((qi - lane) >> 4) + lane;        // word index, lane=g
            mbT[((gw & 63) << 13) + (gw >> 6)] = word;
        }
    }
    for (int off = 32; off; off >>= 1) lcnt += __shfl_down(lcnt, off, 64);
    if ((t & 63) == 0) rc[t >> 6] = lcnt;
    __syncthreads();
    if (t == 0) pcnt[blockIdx.x] = (u64)rc[0] + rc[1] + rc[2] + rc[3];
}

// ---------------- K2: pack W rows into bit columns (transposed, permuted bit order) ----------------
__global__ __launch_bounds__(256) void k2_pack_w(
    const float* __restrict__ W, u64* __restrict__ wbT)
{
    __shared__ float tile[64][65];
    const int j0 = blockIdx.x * 64;
    const int w  = blockIdx.y;            // W-row block: rows w*64..w*64+63
    const int i0 = w * 64;
    const int t = threadIdx.x;
    #pragma unroll
    for (int k = 0; k < 16; ++k) {
        int lin = t + (k << 8);
        int r = lin >> 6, c = lin & 63;
        tile[r][c] = W[(size_t)(i0 + r) * NS + (j0 + c)];
    }
    __syncthreads();
    const int lane = t & 63;
    const int wv = t >> 6;
    const int pr = ((lane & 15) << 2) + (lane >> 4);   // bit l <-> row offset 4*(l&15)+(l>>4)
    for (int jj = wv; jj < 64; jj += 4) {
        u64 bal = __ballot(tile[pr][jj] != 0.0f);
        if (lane == 0) wbT[((size_t)w << 12) + (j0 + jj)] = bal;
    }
}

// ---------------- K3: 128x128 tile popcount-GEMM, 4x16-w stages, fused epilogue ----------------
// NOTE: block-size-only launch bounds. The ",2" waves/EU arg pinned residency to
// ~8 waves/CU (22% occ in R1/R5); R3's ",4" reached 47%. Let resources decide:
// VGPR ~112 + LDS 32KB permit 4 blocks/CU (16 waves).
__global__ __launch_bounds__(256) void k3_main(
    const float* __restrict__ y, const float* __restrict__ yhat,
    const u64* __restrict__ mbT, const u64* __restrict__ wbT,
    double* __restrict__ p3)
{
    __shared__ alignas(16) u64 mT[16 * 128];   // [w][r] linear, 16KB
    __shared__ alignas(16) u64 wT[16 * 128];   // [w][c] XOR-swizzled chunks, 16KB
    const int b0 = blockIdx.x << 7;            // 64 row-tiles
    const int j0 = blockIdx.y << 7;            // 32 col-tiles
    const int t  = threadIdx.x;
    const int r0 = (t >> 4) << 3;              // 8 rows per thread
    const int cj = t & 15;                     // col-group; c0 = cj*8
    const unsigned sx = ((unsigned)cj >> 2) << 4;   // swizzle byte-XOR for q reads

    unsigned cnt[8][8];
    #pragma unroll
    for (int a = 0; a < 8; ++a)
        #pragma unroll
        for (int b = 0; b < 8; ++b) cnt[a][b] = 0;

    char* mB = (char*)mT;
    char* wB = (char*)wT;

    #pragma unroll 1
    for (int s = 0; s < 4; ++s) {
        // load this stage's 16 w-rows into regs (short-lived, consumed immediately)
        u64x2 gm[4], gq[4];
        #pragma unroll
        for (int k = 0; k < 4; ++k) {
            int lin = t + (k << 8);
            int wl = (s << 4) + (lin >> 6), c2 = lin & 63;
            gm[k] = *(const u64x2*)&mbT[((size_t)wl << 13) + b0 + 2 * c2];
            gq[k] = *(const u64x2*)&wbT[((size_t)wl << 12) + j0 + 2 * c2];
        }
        __syncthreads();   // previous stage's compute done before overwrite
        #pragma unroll
        for (int k = 0; k < 4; ++k) {
            int lin = t + (k << 8);
            int wl = lin >> 6, c2 = lin & 63;
            int p = c2 ^ ((c2 >> 4) & 3);
            *(u64x2*)(mB + (wl << 10) + (c2 << 4)) = gm[k];
            *(u64x2*)(wB + (wl << 10) + (p << 4)) = gq[k];
        }
        __syncthreads();

        unsigned mo = (unsigned)(r0 << 3);
        unsigned qs = (unsigned)(cj << 6) + sx;
        #pragma unroll 2
        for (int w = 0; w < 16; ++w) {
            unsigned ml[16], ql[16];
            #pragma unroll
            for (int k = 0; k < 4; ++k) {
                uint4 a = *(const uint4*)(mB + mo + (k << 4));
                ml[4 * k + 0] = a.x; ml[4 * k + 1] = a.y;
                ml[4 * k + 2] = a.z; ml[4 * k + 3] = a.w;
                uint4 b = *(const uint4*)(wB + (qs ^ (unsigned)(k << 4)));
                ql[4 * k + 0] = b.x; ql[4 * k + 1] = b.y;
                ql[4 * k + 2] = b.z; ql[4 * k + 3] = b.w;
            }
            #pragma unroll
            for (int aa = 0; aa < 8; ++aa)
                #pragma unroll
                for (int bb = 0; bb < 8; ++bb) {
                    cnt[aa][bb] += __popc(ml[2 * aa] & ql[2 * bb]);
                    cnt[aa][bb] += __popc(ml[2 * aa + 1] & ql[2 * bb + 1]);
                }
            mo += 1024; qs += 1024;
        }
    }

    // epilogue: part = sum sq * (mask + 0.1*cnt) over this thread's 8x8 patch
    float part = 0.0f;
    const int c0 = cj << 3;
    #pragma unroll
    for (int aa = 0; aa < 8; ++aa) {
        size_t off = ((size_t)(b0 + r0 + aa) << 12) + (size_t)(j0 + c0);
        float ys[8], hs[8];
        *(float4*)&ys[0] = *(const float4*)(y + off);
        *(float4*)&ys[4] = *(const float4*)(y + off + 4);
        *(float4*)&hs[0] = *(const float4*)(yhat + off);
        *(float4*)&hs[4] = *(const float4*)(yhat + off + 4);
        #pragma unroll
        for (int bb = 0; bb < 8; ++bb) {
            float e = ys[bb] - hs[bb];
            float wgt = 0.1f * (float)cnt[aa][bb] + (ys[bb] != 0.0f ? 1.0f : 0.0f);
            part = fmaf(e * e, wgt, part);
        }
    }

    for (int off = 32; off; off >>= 1) part += __shfl_down(part, off, 64);
    float* red = (float*)mT;    // safe: barrier below before aliasing
    __syncthreads();
    if ((t & 63) == 0) red[t >> 6] = part;
    __syncthreads();
    if (t == 0)
        p3[(size_t)blockIdx.y * gridDim.x + blockIdx.x] =
            (double)red[0] + (double)red[1] + (double)red[2] + (double)red[3];
}

// ---------------- K4: final reduce + sqrt ----------------
__global__ __launch_bounds__(256) void k4_final(
    const u64* __restrict__ pcnt, const double* __restrict__ p3, float* __restrict__ out)
{
    __shared__ double rs[4];
    __shared__ u64 rcc[4];
    double s3 = 0.0;
    u64 c = 0;
    for (int i = threadIdx.x; i < 2048; i += 256) { s3 += p3[i]; c += pcnt[i]; }
    for (int off = 32; off; off >>= 1) {
        s3 += __shfl_down(s3, off, 64);
        c  += __shfl_down(c, off, 64);
    }
    int wv = threadIdx.x >> 6;
    if ((threadIdx.x & 63) == 0) { rs[wv] = s3; rcc[wv] = c; }
    __syncthreads();
    if (threadIdx.x == 0) {
        double S3 = rs[0] + rs[1] + rs[2] + rs[3];
        double C  = (double)(rcc[0] + rcc[1] + rcc[2] + rcc[3]);
        out[0] = (float)sqrt(S3 / C + 1e-6);
    }
}

extern "C" void kernel_launch(void* const* d_in, const int* in_sizes, int n_in,
                              void* d_out, int out_size, void* d_ws, size_t ws_size,
                              hipStream_t stream) {
    const float* yhat = (const float*)d_in[0];
    const float* y    = (const float*)d_in[1];
    const float* W    = (const float*)d_in[2];
    char* ws = (char*)d_ws;
    u64*    pcnt = (u64*)(ws + OFF_CNT);
    double* p3   = (double*)(ws + OFF_P3);
    u64*    mbT  = (u64*)(ws + OFF_MB);
    u64*    wbT  = (u64*)(ws + OFF_WB);

    k1_pack_mask<<<dim3(2048), dim3(256), 0, stream>>>(y, mbT, pcnt);
    k2_pack_w<<<dim3(64, 64), dim3(256), 0, stream>>>(W, wbT);
    k3_main<<<dim3(64, 32), dim3(256), 0, stream>>>(y, yhat, mbT, wbT, p3);
    k4_final<<<dim3(1), dim3(256), 0, stream>>>(pcnt, p3, (float*)d_out);
}